// Round 2
// baseline (226.487 us; speedup 1.0000x reference)
//
#include <hip/hip_runtime.h>
#include <math.h>

#define EPSF 1e-8f
#define LAMBDA_C 0.5f

constexpr int Bb = 8;
constexpr int Nn = 32768;
constexpr int Kk = 64;
constexpr int Dd = 64;

// Precompute per (b,k): ss2 = sum_{d=1..63} slots[b,k,d]^2  and  rh = 1/(h+eps).
__global__ void precomp_kernel(const float* __restrict__ slots,
                               const float* __restrict__ horizons,
                               float* __restrict__ pre) {
    int i = blockIdx.x * blockDim.x + threadIdx.x;
    if (i >= Bb * Kk) return;
    const float* srow = slots + (size_t)i * Dd;
    float s2 = 0.f;
    #pragma unroll
    for (int d = 1; d < Dd; ++d) s2 = fmaf(srow[d], srow[d], s2);
    pre[i] = s2;
    pre[Bb * Kk + i] = 1.0f / (horizons[i] + EPSF);
}

// One thread per (b,n). Rank-8-update structure: all 64 logit accumulators
// live in VGPRs (k-loops fully unrolled -> static indexing, no LDS, no
// scratch). Slot operands are block-uniform -> s_load with immediate
// offsets; slots/batch = 16 KiB, sL1-resident. No LDS => occupancy capped
// only by VGPRs (~100 -> ~5 waves/SIMD), vs 10 waves/CU LDS cap before.
__global__ __launch_bounds__(256) void attn_kernel(
    const float* __restrict__ features,
    const float* __restrict__ slots,
    const float* __restrict__ pre,
    float* __restrict__ out)
{
    const int tid = threadIdx.x;
    const int b = blockIdx.x >> 7;               // 128 blocks per batch
    const int n = ((blockIdx.x & 127) << 8) + tid;

    const float* frow = features + ((size_t)b * Nn + n) * Dd;
    const float* sb   = slots + (size_t)b * Kk * Dd;

    float lg[Kk];                                 // full-dot accumulators (VGPRs)
    #pragma unroll
    for (int k = 0; k < Kk; ++k) lg[k] = 0.f;

    const float ft = frow[0];
    float fs2 = 0.f;                              // sum over ALL d; fix up below

    // D in 8 chunks of 8: 2 float4 loads -> 64x8 FMAs (64 independent chains).
    #pragma unroll 2
    for (int c = 0; c < Dd / 8; ++c) {
        float4 f0 = *(const float4*)(frow + c * 8);
        float4 f1 = *(const float4*)(frow + c * 8 + 4);
        float fr[8] = {f0.x, f0.y, f0.z, f0.w, f1.x, f1.y, f1.z, f1.w};
        #pragma unroll
        for (int j = 0; j < 8; ++j) fs2 = fmaf(fr[j], fr[j], fs2);
        const float* sc = sb + c * 8;             // uniform base; k*256B = imm
        #pragma unroll
        for (int k = 0; k < Kk; ++k) {
            const float* srow = sc + k * Dd;
            #pragma unroll
            for (int j = 0; j < 8; ++j)
                lg[k] = fmaf(fr[j], srow[j], lg[k]);
        }
    }
    fs2 = fmaf(-ft, ft, fs2);                     // spatial-only |f|^2

    const float* ss2p = pre + b * Kk;
    const float* rhp  = pre + Bb * Kk + b * Kk;

    // Epilogue per k: logit + running max (no second pass over memory).
    float m = -1e30f;
    #pragma unroll
    for (int k = 0; k < Kk; ++k) {
        float st    = sb[k * Dd];                 // uniform scalar load
        float cross = fmaf(-ft, st, lg[k]);       // spatial cross term
        float dt    = ft - st;
        float dx2   = fmaf(-2.f, cross, fs2 + ss2p[k]);
        dx2 = fmaxf(dx2, 0.f);
        float interval = fmaf(dt, dt, -dx2);
        float adist = sqrtf(fabsf(interval) + EPSF);  // |dist|; sign cancels
        float cone  = (fabsf(dt) - sqrtf(dx2 + EPSF)) * rhp[k];
        // tanh(x) = 1 - 2/(e^{2x}+1): saturates cleanly, no NaN at +/-inf.
        float e  = __expf(2.f * cone);
        float th = 1.f - 2.f * __builtin_amdgcn_rcpf(e + 1.f);
        float l  = fmaf(LAMBDA_C, th, -adist);
        lg[k] = l;
        m = fmaxf(m, l);
    }

    // exp once; reuse for the store pass.
    float s0 = 0.f, s1 = 0.f;
    #pragma unroll
    for (int k = 0; k < Kk; k += 2) {
        float e0 = __expf(lg[k]     - m);
        float e1 = __expf(lg[k + 1] - m);
        lg[k] = e0; lg[k + 1] = e1;
        s0 += e0; s1 += e1;
    }
    const float inv = 1.0f / (s0 + s1);

    float* ob = out + ((size_t)b * Kk) * Nn + n;
    #pragma unroll
    for (int k = 0; k < Kk; ++k)
        ob[(size_t)k * Nn] = lg[k] * inv;
}

extern "C" void kernel_launch(void* const* d_in, const int* in_sizes, int n_in,
                              void* d_out, int out_size, void* d_ws, size_t ws_size,
                              hipStream_t stream) {
    const float* features = (const float*)d_in[0];
    const float* slots    = (const float*)d_in[1];
    const float* horizons = (const float*)d_in[2];
    float* out = (float*)d_out;
    float* pre = (float*)d_ws;   // [0, B*K): ss2, [B*K, 2*B*K): 1/(h+eps)

    hipLaunchKernelGGL(precomp_kernel, dim3(2), dim3(256), 0, stream,
                       slots, horizons, pre);
    hipLaunchKernelGGL(attn_kernel, dim3((Bb * Nn) / 256), dim3(256), 0, stream,
                       features, slots, pre, out);
}